// Round 14
// baseline (238.058 us; speedup 1.0000x reference)
//
#include <hip/hip_runtime.h>
#include <stdint.h>

#define KSTEPS 24              // 768 / 32
#define TOKENS 16384           // B*S

typedef short short8 __attribute__((ext_vector_type(8)));
typedef float fx4 __attribute__((ext_vector_type(4)));
typedef unsigned short u16;
typedef u16 u16x4 __attribute__((ext_vector_type(4)));

static __device__ __forceinline__ u16 f2bf(float f) {
  union { float f; unsigned u; } v; v.f = f;
  return (u16)((v.u + 0x7fffu + ((v.u >> 16) & 1u)) >> 16);
}

// cheap round (half-up) for the attention hot loop: p is post-exp2, tolerance-safe
static __device__ __forceinline__ u16 p2bf(float f) {
  union { float f; unsigned u; } v; v.f = f;
  return (u16)((v.u + 0x8000u) >> 16);
}

static __device__ __forceinline__ fx4 mfma16(short8 a, short8 b, fx4 c) {
  return __builtin_amdgcn_mfma_f32_16x16x32_bf16(a, b, c, 0, 0, 0);
}

// async global->LDS, 16B/lane; lds dest = wave-uniform base + lane*16
static __device__ __forceinline__ void async16(const void* g, void* l) {
  __builtin_amdgcn_global_load_lds(
      (const __attribute__((address_space(1))) void*)g,
      (__attribute__((address_space(3))) void*)(unsigned int)(uintptr_t)l,
      16, 0, 0);
}

// ---------------- prep: W[768][64] fp32 (q,k,v) -> bf16 pre-fragmented B-operand layout
__global__ void prep_w_kernel(const float* __restrict__ Wq, const float* __restrict__ Wk,
                              const float* __restrict__ Wv, u16* __restrict__ wfrag) {
  int idx  = blockIdx.x * 256 + threadIdx.x;   // 72*256 = 18432 = 3*24*4*64
  int lane = idx & 63;
  int fid  = idx >> 6;
  int nt   = fid & 3;
  int ks   = (fid >> 2) % KSTEPS;
  int mat  = fid / (KSTEPS * 4);
  const float* W = (mat == 0) ? Wq : (mat == 1) ? Wk : Wv;
  int n  = nt * 16 + (lane & 15);
  int k0 = ks * 32 + (lane >> 4) * 8;
  short8 out;
#pragma unroll
  for (int j = 0; j < 8; j++) out[j] = (short)f2bf(W[(size_t)(k0 + j) * 64 + n]);
  *(short8*)(wfrag + (size_t)idx * 8) = out;
}

// ---------------- projection GEMM v4: W RESIDENT IN REGISTERS, no LDS, no barriers.
// Block = 12 waves (768 thr), one per (mat,nt) f-tile; each wave holds its 24
// W-frags (96 VGPR) and streams x with depth-2 register prefetch. All 12 waves
// read the same x rows simultaneously -> L1/L2-hot. 256 blocks = 1/CU, no tail.
__global__ __launch_bounds__(768, 3) void proj_kernel(const float* __restrict__ x,
                                                      const u16* __restrict__ wfrag,
                                                      u16* __restrict__ qb,
                                                      u16* __restrict__ kb,
                                                      u16* __restrict__ vT) {
  int w = threadIdx.x >> 6, lane = threadIdx.x & 63;
  int ln = lane & 15, quad = lane >> 4;
  int m = w >> 2, nt = w & 3;         // this wave's f-tile

  // resident W fragments, all 24 ksteps (96 VGPRs)
  short8 wreg[KSTEPS];
  const u16* wp = wfrag + ((size_t)m * KSTEPS * 256 + nt * 64 + lane) * 8;
#pragma unroll
  for (int ks = 0; ks < KSTEPS; ks++)
    wreg[ks] = *(const short8*)(wp + (size_t)ks * 2048);

  for (int i = 0; i < 4; i++) {       // 4 token-tiles of 16 per block
    int s0 = (blockIdx.x * 4 + i) * 16;
    const float* xp = x + (size_t)(s0 + ln) * 768 + quad * 8;

    fx4 acc = (fx4){0.f, 0.f, 0.f, 0.f};
    fx4 xr[2][2];
#pragma unroll
    for (int s = 0; s < 2; s++) {
      xr[s][0] = *(const fx4*)(xp + s * 32);
      xr[s][1] = *(const fx4*)(xp + s * 32 + 4);
    }
#pragma unroll 4
    for (int ks = 0; ks < KSTEPS; ks++) {
      int c = ks & 1;
      short8 af;
#pragma unroll
      for (int j = 0; j < 4; j++) {
        af[j]     = (short)f2bf(xr[c][0][j]);
        af[4 + j] = (short)f2bf(xr[c][1][j]);
      }
      fx4 nx0, nx1;
      if (ks < KSTEPS - 2) {
        nx0 = *(const fx4*)(xp + (ks + 2) * 32);
        nx1 = *(const fx4*)(xp + (ks + 2) * 32 + 4);
      }
      acc = mfma16(af, wreg[ks], acc);
      if (ks < KSTEPS - 2) { xr[c][0] = nx0; xr[c][1] = nx1; }
    }

    // epilogue: C/D layout col = lane&15, row = quad*4 + reg
    int tok0 = s0 + quad * 4;
    int d = nt * 16 + ln;
    if (m == 0) {
      // Q pre-scaled by 0.125 * log2(e): scores land in exp2 domain
#pragma unroll
      for (int reg = 0; reg < 4; reg++)
        qb[(size_t)(tok0 + reg) * 64 + d] = f2bf(acc[reg] * 0.180336887f);
    } else if (m == 1) {
#pragma unroll
      for (int reg = 0; reg < 4; reg++)
        kb[(size_t)(tok0 + reg) * 64 + d] = f2bf(acc[reg]);
    } else {
      int b = tok0 >> 12, s = tok0 & 4095;
      u16x4 vp;
#pragma unroll
      for (int reg = 0; reg < 4; reg++) vp[reg] = f2bf(acc[reg]);
      *(u16x4*)(vT + ((size_t)b * 64 + d) * 4096 + s) = vp;
    }
  }
}

// ---------------- flash attention v9 (unchanged): 32 Q-rows/wave, K+V DMA-staged
__global__ __launch_bounds__(256, 3) void attn_kernel(const u16* __restrict__ qb,
                                                      const u16* __restrict__ kb,
                                                      const u16* __restrict__ vT,
                                                      float* __restrict__ o0g,
                                                      float* __restrict__ po5,
                                                      float* __restrict__ mlb) {
  __shared__ u16 Kstg[2][4096];       // [buf][64 keys x 64 d]   16KB
  __shared__ u16 Vstg[2][4096];       // [buf][64 d x 64 keys]   16KB (V^T)
  __shared__ u16 Ps[4][32 * 72];      // per-wave P (32 rows), padded: 18KB

  int w = threadIdx.x >> 6, lane = threadIdx.x & 63;
  int ln = lane & 15, quad = lane >> 4;
  int band = 31 - blockIdx.x;         // 128-row band
  int b = blockIdx.y, z = blockIdx.z; // batch, split-K sixth
  int q0 = band * 128;
  int qw = q0 + w * 32;               // this wave's first Q-row (owns 32 rows)

  const u16* qbb = qb + (size_t)b * 4096 * 64;
  const u16* kbb = kb + (size_t)b * 4096 * 64;
  const u16* vtb = vT + (size_t)b * 64 * 4096;

  short8 qf0a = *(const short8*)(qbb + (size_t)(qw + ln) * 64 + quad * 8);
  short8 qf1a = *(const short8*)(qbb + (size_t)(qw + ln) * 64 + 32 + quad * 8);
  short8 qf0b = *(const short8*)(qbb + (size_t)(qw + 16 + ln) * 64 + quad * 8);
  short8 qf1b = *(const short8*)(qbb + (size_t)(qw + 16 + ln) * 64 + 32 + quad * 8);

  short8 ones;
#pragma unroll
  for (int j = 0; j < 8; j++) ones[j] = (short)0x3F80;   // bf16 1.0

  fx4 oa[4], ob[4];
#pragma unroll
  for (int j = 0; j < 4; j++) { oa[j] = (fx4){0.f,0.f,0.f,0.f}; ob[j] = (fx4){0.f,0.f,0.f,0.f}; }
  float la[4] = {0.f,0.f,0.f,0.f}, lb[4] = {0.f,0.f,0.f,0.f};

  int n = 2 * band + 2;               // 64-key tiles this band needs
  int c = (n + 5) / 6;                // tiles per split-K sixth
  int lo = z * c; if (lo > n) lo = n;
  int hi = lo + c; if (hi > n) hi = n;

  int t0c = w * 64 + lane;
  if (lo < hi) {
#pragma unroll
    for (int j = 0; j < 2; j++) {
      int cc = t0c + j * 256;
      int row = cc >> 3, slot = cc & 7, sw_ = (slot ^ (row & 7)) * 8;
      async16(kbb + ((size_t)lo * 64 + row) * 64 + sw_, (char*)Kstg[0] + cc * 16);
      async16(vtb + (size_t)row * 4096 + lo * 64 + sw_, (char*)Vstg[0] + cc * 16);
    }
  }

  for (int t = lo; t < hi; t++) {
    __syncthreads();                  // publishes buf (t-lo)&1
    if (t + 1 < hi) {
      int nb = (t - lo + 1) & 1;
#pragma unroll
      for (int j = 0; j < 2; j++) {
        int cc = t0c + j * 256;
        int row = cc >> 3, slot = cc & 7, sw_ = (slot ^ (row & 7)) * 8;
        async16(kbb + ((size_t)(t + 1) * 64 + row) * 64 + sw_, (char*)Kstg[nb] + cc * 16);
        async16(vtb + (size_t)row * 4096 + (t + 1) * 64 + sw_, (char*)Vstg[nb] + cc * 16);
      }
    }
    if (64 * t > qw + 31) continue;   // tile entirely above this wave's rows

    const u16* Kb = Kstg[(t - lo) & 1];
    const u16* Vb = Vstg[(t - lo) & 1];

    fx4 sAa[4], sAb[4];
#pragma unroll
    for (int nt = 0; nt < 4; nt++) {
      int row = nt * 16 + ln;
      int s0_ = quad ^ (row & 7), s1_ = (quad + 4) ^ (row & 7);
      short8 kf0 = *(const short8*)(Kb + (row * 8 + s0_) * 8);
      short8 kf1 = *(const short8*)(Kb + (row * 8 + s1_) * 8);
      sAa[nt] = mfma16(qf0a, kf0, (fx4){0.f,0.f,0.f,0.f});
      sAa[nt] = mfma16(qf1a, kf1, sAa[nt]);
      sAb[nt] = mfma16(qf0b, kf0, (fx4){0.f,0.f,0.f,0.f});
      sAb[nt] = mfma16(qf1b, kf1, sAb[nt]);
    }

    if (64 * t + 63 > qw) {
#pragma unroll
      for (int nt = 0; nt < 4; nt++)
#pragma unroll
        for (int reg = 0; reg < 4; reg++) {
          int col = t * 64 + nt * 16 + ln;
          int ra = qw + quad * 4 + reg;
          if (col > ra) sAa[nt][reg] = -1e30f;
          if (col > ra + 16) sAb[nt][reg] = -1e30f;
        }
    }

#pragma unroll
    for (int nt = 0; nt < 4; nt++)
#pragma unroll
      for (int reg = 0; reg < 4; reg++) {
        Ps[w][(quad * 4 + reg) * 72 + nt * 16 + ln] =
            p2bf(__builtin_amdgcn_exp2f(sAa[nt][reg]));
        Ps[w][(16 + quad * 4 + reg) * 72 + nt * 16 + ln] =
            p2bf(__builtin_amdgcn_exp2f(sAb[nt][reg]));
      }

    short8 pf0a = *(const short8*)(&Ps[w][ln * 72 + quad * 8]);
    short8 pf1a = *(const short8*)(&Ps[w][ln * 72 + 32 + quad * 8]);
    short8 pf0b = *(const short8*)(&Ps[w][(16 + ln) * 72 + quad * 8]);
    short8 pf1b = *(const short8*)(&Ps[w][(16 + ln) * 72 + 32 + quad * 8]);

    fx4 lacc = mfma16(pf0a, ones, (fx4){0.f,0.f,0.f,0.f});
    lacc = mfma16(pf1a, ones, lacc);
#pragma unroll
    for (int reg = 0; reg < 4; reg++) la[reg] += lacc[reg];
    lacc = mfma16(pf0b, ones, (fx4){0.f,0.f,0.f,0.f});
    lacc = mfma16(pf1b, ones, lacc);
#pragma unroll
    for (int reg = 0; reg < 4; reg++) lb[reg] += lacc[reg];

#pragma unroll
    for (int nt2 = 0; nt2 < 4; nt2++) {
      int row = nt2 * 16 + ln;
      int s0_ = quad ^ (row & 7), s1_ = (quad + 4) ^ (row & 7);
      short8 vf0 = *(const short8*)(Vb + (row * 8 + s0_) * 8);
      short8 vf1 = *(const short8*)(Vb + (row * 8 + s1_) * 8);
      oa[nt2] = mfma16(pf0a, vf0, oa[nt2]);
      oa[nt2] = mfma16(pf1a, vf1, oa[nt2]);
      ob[nt2] = mfma16(pf0b, vf0, ob[nt2]);
      ob[nt2] = mfma16(pf1b, vf1, ob[nt2]);
    }
  }

  float* dst = (z == 0) ? o0g : (po5 + (size_t)(z - 1) * 4 * 4096 * 64);
#pragma unroll
  for (int nt2 = 0; nt2 < 4; nt2++)
#pragma unroll
    for (int reg = 0; reg < 4; reg++) {
      int ra = qw + quad * 4 + reg;
      dst[((size_t)b * 4096 + ra) * 64 + nt2 * 16 + ln] = oa[nt2][reg];
      dst[((size_t)b * 4096 + ra + 16) * 64 + nt2 * 16 + ln] = ob[nt2][reg];
    }
  if (ln == 0) {
#pragma unroll
    for (int reg = 0; reg < 4; reg++) {
      int ra = qw + quad * 4 + reg;
      mlb[((size_t)z * 4 + b) * 4096 + ra] = la[reg];
      mlb[((size_t)z * 4 + b) * 4096 + ra + 16] = lb[reg];
    }
  }
}

// ---------------- merge the six split-K parts: out = Σo_z / Σl_z
__global__ __launch_bounds__(256) void merge_kernel(float* __restrict__ out,
                                                    const float* __restrict__ po5,
                                                    const float* __restrict__ mlb) {
  int qt = blockIdx.x, b = blockIdx.y;
  int r = threadIdx.x >> 3;
  int c = (threadIdx.x & 7) * 8;
  size_t row = (size_t)b * 4096 + qt * 32 + r;
  float l = mlb[row];
#pragma unroll
  for (int z = 1; z < 6; z++) l += mlb[(size_t)z * 4 * 4096 + row];
  float inv = 1.0f / l;
  float* op = out + row * 64 + c;
  fx4 u0 = *(fx4*)op, u1 = *(fx4*)(op + 4);
#pragma unroll
  for (int z = 1; z < 6; z++) {
    const float* pp = po5 + (size_t)(z - 1) * 4 * 4096 * 64 + row * 64 + c;
    fx4 v0 = *(const fx4*)pp, v1 = *(const fx4*)(pp + 4);
#pragma unroll
    for (int j = 0; j < 4; j++) { u0[j] += v0[j]; u1[j] += v1[j]; }
  }
#pragma unroll
  for (int j = 0; j < 4; j++) { u0[j] *= inv; u1[j] *= inv; }
  *(fx4*)op = u0;
  *(fx4*)(op + 4) = u1;
}

extern "C" void kernel_launch(void* const* d_in, const int* in_sizes, int n_in,
                              void* d_out, int out_size, void* d_ws, size_t ws_size,
                              hipStream_t stream) {
  const float* x  = (const float*)d_in[0];
  const float* Wq = (const float*)d_in[1];
  const float* Wk = (const float*)d_in[2];
  const float* Wv = (const float*)d_in[3];

  u16* qbw = (u16*)d_ws;                          // [16384][64] bf16, 2MB
  u16* kbw = qbw + (size_t)TOKENS * 64;           // 2MB
  u16* vtw = kbw + (size_t)TOKENS * 64;           // 2MB
  u16* wfr = vtw + (size_t)TOKENS * 64;           // 288KB
  float* po5 = (float*)(wfr + (size_t)3 * KSTEPS * 256 * 8);  // 5x [4][4096][64] fp32, 20MB
  float* mlb = po5 + (size_t)5 * 4 * 4096 * 64;   // [6][4][4096] float, 384KB

  prep_w_kernel<<<72, 256, 0, stream>>>(Wq, Wk, Wv, wfr);
  proj_kernel<<<TOKENS / 64, 768, 0, stream>>>(x, wfr, qbw, kbw, vtw);
  attn_kernel<<<dim3(32, 4, 6), 256, 0, stream>>>(qbw, kbw, vtw,
                                                  (float*)d_out, po5, mlb);
  merge_kernel<<<dim3(128, 4), 256, 0, stream>>>((float*)d_out, po5, mlb);
}

// Round 15
// 182.133 us; speedup vs baseline: 1.3071x; 1.3071x over previous
//
#include <hip/hip_runtime.h>
#include <stdint.h>

#define KSTEPS 24              // 768 / 32
#define TOKENS 16384           // B*S

typedef short short8 __attribute__((ext_vector_type(8)));
typedef float fx4 __attribute__((ext_vector_type(4)));
typedef unsigned short u16;
typedef u16 u16x4 __attribute__((ext_vector_type(4)));

static __device__ __forceinline__ u16 f2bf(float f) {
  union { float f; unsigned u; } v; v.f = f;
  return (u16)((v.u + 0x7fffu + ((v.u >> 16) & 1u)) >> 16);
}

// cheap round (half-up) for the attention hot loop: p is post-exp2, tolerance-safe
static __device__ __forceinline__ u16 p2bf(float f) {
  union { float f; unsigned u; } v; v.f = f;
  return (u16)((v.u + 0x8000u) >> 16);
}

static __device__ __forceinline__ fx4 mfma16(short8 a, short8 b, fx4 c) {
  return __builtin_amdgcn_mfma_f32_16x16x32_bf16(a, b, c, 0, 0, 0);
}

// async global->LDS, 16B/lane; lds dest = wave-uniform base + lane*16
static __device__ __forceinline__ void async16(const void* g, void* l) {
  __builtin_amdgcn_global_load_lds(
      (const __attribute__((address_space(1))) void*)g,
      (__attribute__((address_space(3))) void*)(unsigned int)(uintptr_t)l,
      16, 0, 0);
}

// ---------------- prep: W[768][64] fp32 (q,k,v) -> bf16 pre-fragmented B-operand layout
__global__ void prep_w_kernel(const float* __restrict__ Wq, const float* __restrict__ Wk,
                              const float* __restrict__ Wv, u16* __restrict__ wfrag) {
  int idx  = blockIdx.x * 256 + threadIdx.x;   // 72*256 = 18432 = 3*24*4*64
  int lane = idx & 63;
  int fid  = idx >> 6;
  int nt   = fid & 3;
  int ks   = (fid >> 2) % KSTEPS;
  int mat  = fid / (KSTEPS * 4);
  const float* W = (mat == 0) ? Wq : (mat == 1) ? Wk : Wv;
  int n  = nt * 16 + (lane & 15);
  int k0 = ks * 32 + (lane >> 4) * 8;
  short8 out;
#pragma unroll
  for (int j = 0; j < 8; j++) out[j] = (short)f2bf(W[(size_t)(k0 + j) * 64 + n]);
  *(short8*)(wfrag + (size_t)idx * 8) = out;
}

// ---------------- projection GEMM v4b: W resident in registers — FULLY UNROLLED
// kstep loop so wreg[ks] indices are compile-time constants (r14's partial
// unroll made them dynamic -> scratch spill, 80MB of spill traffic).
// Block = 12 waves (768 thr), one per (mat,nt) f-tile; no LDS, no barriers.
__global__ __launch_bounds__(768, 3) void proj_kernel(const float* __restrict__ x,
                                                      const u16* __restrict__ wfrag,
                                                      u16* __restrict__ qb,
                                                      u16* __restrict__ kb,
                                                      u16* __restrict__ vT) {
  int w = threadIdx.x >> 6, lane = threadIdx.x & 63;
  int ln = lane & 15, quad = lane >> 4;
  int m = w >> 2, nt = w & 3;         // this wave's f-tile

  // resident W fragments, all 24 ksteps (96 VGPRs) — indices constant below
  short8 wreg[KSTEPS];
  const u16* wp = wfrag + ((size_t)m * KSTEPS * 256 + nt * 64 + lane) * 8;
#pragma unroll
  for (int ks = 0; ks < KSTEPS; ks++)
    wreg[ks] = *(const short8*)(wp + (size_t)ks * 2048);

  for (int i = 0; i < 4; i++) {       // 4 token-tiles of 16 per block
    int s0 = (blockIdx.x * 4 + i) * 16;
    const float* xp = x + (size_t)(s0 + ln) * 768 + quad * 8;

    fx4 acc = (fx4){0.f, 0.f, 0.f, 0.f};
    fx4 xr0[2], xr1[2];
#pragma unroll
    for (int s = 0; s < 2; s++) {
      xr0[s] = *(const fx4*)(xp + s * 32);
      xr1[s] = *(const fx4*)(xp + s * 32 + 4);
    }
#pragma unroll
    for (int ks = 0; ks < KSTEPS; ks++) {   // FULL unroll: wreg/xr indices constant
      int c = ks & 1;
      short8 af;
#pragma unroll
      for (int j = 0; j < 4; j++) {
        af[j]     = (short)f2bf(xr0[c][j]);
        af[4 + j] = (short)f2bf(xr1[c][j]);
      }
      fx4 n0, n1;
      if (ks < KSTEPS - 2) {
        n0 = *(const fx4*)(xp + (ks + 2) * 32);
        n1 = *(const fx4*)(xp + (ks + 2) * 32 + 4);
      }
      acc = mfma16(af, wreg[ks], acc);
      if (ks < KSTEPS - 2) { xr0[c] = n0; xr1[c] = n1; }
    }

    // epilogue: C/D layout col = lane&15, row = quad*4 + reg
    int tok0 = s0 + quad * 4;
    int d = nt * 16 + ln;
    if (m == 0) {
      // Q pre-scaled by 0.125 * log2(e): scores land in exp2 domain
#pragma unroll
      for (int reg = 0; reg < 4; reg++)
        qb[(size_t)(tok0 + reg) * 64 + d] = f2bf(acc[reg] * 0.180336887f);
    } else if (m == 1) {
#pragma unroll
      for (int reg = 0; reg < 4; reg++)
        kb[(size_t)(tok0 + reg) * 64 + d] = f2bf(acc[reg]);
    } else {
      int b = tok0 >> 12, s = tok0 & 4095;
      u16x4 vp;
#pragma unroll
      for (int reg = 0; reg < 4; reg++) vp[reg] = f2bf(acc[reg]);
      *(u16x4*)(vT + ((size_t)b * 64 + d) * 4096 + s) = vp;
    }
  }
}

// ---------------- flash attention v9 (unchanged): 32 Q-rows/wave, K+V DMA-staged
__global__ __launch_bounds__(256, 3) void attn_kernel(const u16* __restrict__ qb,
                                                      const u16* __restrict__ kb,
                                                      const u16* __restrict__ vT,
                                                      float* __restrict__ o0g,
                                                      float* __restrict__ po5,
                                                      float* __restrict__ mlb) {
  __shared__ u16 Kstg[2][4096];       // [buf][64 keys x 64 d]   16KB
  __shared__ u16 Vstg[2][4096];       // [buf][64 d x 64 keys]   16KB (V^T)
  __shared__ u16 Ps[4][32 * 72];      // per-wave P (32 rows), padded: 18KB

  int w = threadIdx.x >> 6, lane = threadIdx.x & 63;
  int ln = lane & 15, quad = lane >> 4;
  int band = 31 - blockIdx.x;         // 128-row band
  int b = blockIdx.y, z = blockIdx.z; // batch, split-K sixth
  int q0 = band * 128;
  int qw = q0 + w * 32;               // this wave's first Q-row (owns 32 rows)

  const u16* qbb = qb + (size_t)b * 4096 * 64;
  const u16* kbb = kb + (size_t)b * 4096 * 64;
  const u16* vtb = vT + (size_t)b * 64 * 4096;

  short8 qf0a = *(const short8*)(qbb + (size_t)(qw + ln) * 64 + quad * 8);
  short8 qf1a = *(const short8*)(qbb + (size_t)(qw + ln) * 64 + 32 + quad * 8);
  short8 qf0b = *(const short8*)(qbb + (size_t)(qw + 16 + ln) * 64 + quad * 8);
  short8 qf1b = *(const short8*)(qbb + (size_t)(qw + 16 + ln) * 64 + 32 + quad * 8);

  short8 ones;
#pragma unroll
  for (int j = 0; j < 8; j++) ones[j] = (short)0x3F80;   // bf16 1.0

  fx4 oa[4], ob[4];
#pragma unroll
  for (int j = 0; j < 4; j++) { oa[j] = (fx4){0.f,0.f,0.f,0.f}; ob[j] = (fx4){0.f,0.f,0.f,0.f}; }
  float la[4] = {0.f,0.f,0.f,0.f}, lb[4] = {0.f,0.f,0.f,0.f};

  int n = 2 * band + 2;               // 64-key tiles this band needs
  int c = (n + 5) / 6;                // tiles per split-K sixth
  int lo = z * c; if (lo > n) lo = n;
  int hi = lo + c; if (hi > n) hi = n;

  int t0c = w * 64 + lane;
  if (lo < hi) {
#pragma unroll
    for (int j = 0; j < 2; j++) {
      int cc = t0c + j * 256;
      int row = cc >> 3, slot = cc & 7, sw_ = (slot ^ (row & 7)) * 8;
      async16(kbb + ((size_t)lo * 64 + row) * 64 + sw_, (char*)Kstg[0] + cc * 16);
      async16(vtb + (size_t)row * 4096 + lo * 64 + sw_, (char*)Vstg[0] + cc * 16);
    }
  }

  for (int t = lo; t < hi; t++) {
    __syncthreads();                  // publishes buf (t-lo)&1
    if (t + 1 < hi) {
      int nb = (t - lo + 1) & 1;
#pragma unroll
      for (int j = 0; j < 2; j++) {
        int cc = t0c + j * 256;
        int row = cc >> 3, slot = cc & 7, sw_ = (slot ^ (row & 7)) * 8;
        async16(kbb + ((size_t)(t + 1) * 64 + row) * 64 + sw_, (char*)Kstg[nb] + cc * 16);
        async16(vtb + (size_t)row * 4096 + (t + 1) * 64 + sw_, (char*)Vstg[nb] + cc * 16);
      }
    }
    if (64 * t > qw + 31) continue;   // tile entirely above this wave's rows

    const u16* Kb = Kstg[(t - lo) & 1];
    const u16* Vb = Vstg[(t - lo) & 1];

    fx4 sAa[4], sAb[4];
#pragma unroll
    for (int nt = 0; nt < 4; nt++) {
      int row = nt * 16 + ln;
      int s0_ = quad ^ (row & 7), s1_ = (quad + 4) ^ (row & 7);
      short8 kf0 = *(const short8*)(Kb + (row * 8 + s0_) * 8);
      short8 kf1 = *(const short8*)(Kb + (row * 8 + s1_) * 8);
      sAa[nt] = mfma16(qf0a, kf0, (fx4){0.f,0.f,0.f,0.f});
      sAa[nt] = mfma16(qf1a, kf1, sAa[nt]);
      sAb[nt] = mfma16(qf0b, kf0, (fx4){0.f,0.f,0.f,0.f});
      sAb[nt] = mfma16(qf1b, kf1, sAb[nt]);
    }

    if (64 * t + 63 > qw) {
#pragma unroll
      for (int nt = 0; nt < 4; nt++)
#pragma unroll
        for (int reg = 0; reg < 4; reg++) {
          int col = t * 64 + nt * 16 + ln;
          int ra = qw + quad * 4 + reg;
          if (col > ra) sAa[nt][reg] = -1e30f;
          if (col > ra + 16) sAb[nt][reg] = -1e30f;
        }
    }

#pragma unroll
    for (int nt = 0; nt < 4; nt++)
#pragma unroll
      for (int reg = 0; reg < 4; reg++) {
        Ps[w][(quad * 4 + reg) * 72 + nt * 16 + ln] =
            p2bf(__builtin_amdgcn_exp2f(sAa[nt][reg]));
        Ps[w][(16 + quad * 4 + reg) * 72 + nt * 16 + ln] =
            p2bf(__builtin_amdgcn_exp2f(sAb[nt][reg]));
      }

    short8 pf0a = *(const short8*)(&Ps[w][ln * 72 + quad * 8]);
    short8 pf1a = *(const short8*)(&Ps[w][ln * 72 + 32 + quad * 8]);
    short8 pf0b = *(const short8*)(&Ps[w][(16 + ln) * 72 + quad * 8]);
    short8 pf1b = *(const short8*)(&Ps[w][(16 + ln) * 72 + 32 + quad * 8]);

    fx4 lacc = mfma16(pf0a, ones, (fx4){0.f,0.f,0.f,0.f});
    lacc = mfma16(pf1a, ones, lacc);
#pragma unroll
    for (int reg = 0; reg < 4; reg++) la[reg] += lacc[reg];
    lacc = mfma16(pf0b, ones, (fx4){0.f,0.f,0.f,0.f});
    lacc = mfma16(pf1b, ones, lacc);
#pragma unroll
    for (int reg = 0; reg < 4; reg++) lb[reg] += lacc[reg];

#pragma unroll
    for (int nt2 = 0; nt2 < 4; nt2++) {
      int row = nt2 * 16 + ln;
      int s0_ = quad ^ (row & 7), s1_ = (quad + 4) ^ (row & 7);
      short8 vf0 = *(const short8*)(Vb + (row * 8 + s0_) * 8);
      short8 vf1 = *(const short8*)(Vb + (row * 8 + s1_) * 8);
      oa[nt2] = mfma16(pf0a, vf0, oa[nt2]);
      oa[nt2] = mfma16(pf1a, vf1, oa[nt2]);
      ob[nt2] = mfma16(pf0b, vf0, ob[nt2]);
      ob[nt2] = mfma16(pf1b, vf1, ob[nt2]);
    }
  }

  float* dst = (z == 0) ? o0g : (po5 + (size_t)(z - 1) * 4 * 4096 * 64);
#pragma unroll
  for (int nt2 = 0; nt2 < 4; nt2++)
#pragma unroll
    for (int reg = 0; reg < 4; reg++) {
      int ra = qw + quad * 4 + reg;
      dst[((size_t)b * 4096 + ra) * 64 + nt2 * 16 + ln] = oa[nt2][reg];
      dst[((size_t)b * 4096 + ra + 16) * 64 + nt2 * 16 + ln] = ob[nt2][reg];
    }
  if (ln == 0) {
#pragma unroll
    for (int reg = 0; reg < 4; reg++) {
      int ra = qw + quad * 4 + reg;
      mlb[((size_t)z * 4 + b) * 4096 + ra] = la[reg];
      mlb[((size_t)z * 4 + b) * 4096 + ra + 16] = lb[reg];
    }
  }
}

// ---------------- merge the six split-K parts: out = Σo_z / Σl_z
__global__ __launch_bounds__(256) void merge_kernel(float* __restrict__ out,
                                                    const float* __restrict__ po5,
                                                    const float* __restrict__ mlb) {
  int qt = blockIdx.x, b = blockIdx.y;
  int r = threadIdx.x >> 3;
  int c = (threadIdx.x & 7) * 8;
  size_t row = (size_t)b * 4096 + qt * 32 + r;
  float l = mlb[row];
#pragma unroll
  for (int z = 1; z < 6; z++) l += mlb[(size_t)z * 4 * 4096 + row];
  float inv = 1.0f / l;
  float* op = out + row * 64 + c;
  fx4 u0 = *(fx4*)op, u1 = *(fx4*)(op + 4);
#pragma unroll
  for (int z = 1; z < 6; z++) {
    const float* pp = po5 + (size_t)(z - 1) * 4 * 4096 * 64 + row * 64 + c;
    fx4 v0 = *(const fx4*)pp, v1 = *(const fx4*)(pp + 4);
#pragma unroll
    for (int j = 0; j < 4; j++) { u0[j] += v0[j]; u1[j] += v1[j]; }
  }
#pragma unroll
  for (int j = 0; j < 4; j++) { u0[j] *= inv; u1[j] *= inv; }
  *(fx4*)op = u0;
  *(fx4*)(op + 4) = u1;
}

extern "C" void kernel_launch(void* const* d_in, const int* in_sizes, int n_in,
                              void* d_out, int out_size, void* d_ws, size_t ws_size,
                              hipStream_t stream) {
  const float* x  = (const float*)d_in[0];
  const float* Wq = (const float*)d_in[1];
  const float* Wk = (const float*)d_in[2];
  const float* Wv = (const float*)d_in[3];

  u16* qbw = (u16*)d_ws;                          // [16384][64] bf16, 2MB
  u16* kbw = qbw + (size_t)TOKENS * 64;           // 2MB
  u16* vtw = kbw + (size_t)TOKENS * 64;           // 2MB
  u16* wfr = vtw + (size_t)TOKENS * 64;           // 288KB
  float* po5 = (float*)(wfr + (size_t)3 * KSTEPS * 256 * 8);  // 5x [4][4096][64] fp32, 20MB
  float* mlb = po5 + (size_t)5 * 4 * 4096 * 64;   // [6][4][4096] float, 384KB

  prep_w_kernel<<<72, 256, 0, stream>>>(Wq, Wk, Wv, wfr);
  proj_kernel<<<TOKENS / 64, 768, 0, stream>>>(x, wfr, qbw, kbw, vtw);
  attn_kernel<<<dim3(32, 4, 6), 256, 0, stream>>>(qbw, kbw, vtw,
                                                  (float*)d_out, po5, mlb);
  merge_kernel<<<dim3(128, 4), 256, 0, stream>>>((float*)d_out, po5, mlb);
}

// Round 16
// 130.857 us; speedup vs baseline: 1.8192x; 1.3919x over previous
//
#include <hip/hip_runtime.h>
#include <stdint.h>

#define KSTEPS 24              // 768 / 32
#define TOKENS 16384           // B*S

typedef short short8 __attribute__((ext_vector_type(8)));
typedef float fx4 __attribute__((ext_vector_type(4)));
typedef unsigned short u16;
typedef u16 u16x4 __attribute__((ext_vector_type(4)));

static __device__ __forceinline__ u16 f2bf(float f) {
  union { float f; unsigned u; } v; v.f = f;
  return (u16)((v.u + 0x7fffu + ((v.u >> 16) & 1u)) >> 16);
}

// cheap round (half-up) for the attention hot loop: p is post-exp2, tolerance-safe
static __device__ __forceinline__ u16 p2bf(float f) {
  union { float f; unsigned u; } v; v.f = f;
  return (u16)((v.u + 0x8000u) >> 16);
}

static __device__ __forceinline__ fx4 mfma16(short8 a, short8 b, fx4 c) {
  return __builtin_amdgcn_mfma_f32_16x16x32_bf16(a, b, c, 0, 0, 0);
}

// async global->LDS, 16B/lane; lds dest = wave-uniform base + lane*16
static __device__ __forceinline__ void async16(const void* g, void* l) {
  __builtin_amdgcn_global_load_lds(
      (const __attribute__((address_space(1))) void*)g,
      (__attribute__((address_space(3))) void*)(unsigned int)(uintptr_t)l,
      16, 0, 0);
}

// ---------------- prep: W[768][64] fp32 (q,k,v) -> bf16 pre-fragmented B-operand layout
__global__ void prep_w_kernel(const float* __restrict__ Wq, const float* __restrict__ Wk,
                              const float* __restrict__ Wv, u16* __restrict__ wfrag) {
  int idx  = blockIdx.x * 256 + threadIdx.x;   // 72*256 = 18432 = 3*24*4*64
  int lane = idx & 63;
  int fid  = idx >> 6;
  int nt   = fid & 3;
  int ks   = (fid >> 2) % KSTEPS;
  int mat  = fid / (KSTEPS * 4);
  const float* W = (mat == 0) ? Wq : (mat == 1) ? Wk : Wv;
  int n  = nt * 16 + (lane & 15);
  int k0 = ks * 32 + (lane >> 4) * 8;
  short8 out;
#pragma unroll
  for (int j = 0; j < 8; j++) out[j] = (short)f2bf(W[(size_t)(k0 + j) * 64 + n]);
  *(short8*)(wfrag + (size_t)idx * 8) = out;
}

// ---------------- projection GEMM v5: LDS-staged (the only staging path that
// works on this chip — register-resident W failed 3x: spill or remat), with
// BK=64: 12 barrier rounds instead of 24, 2 ksteps & 12 MFMAs/wave per round.
// 32 tok/block, 256 thr, 4 waves = 2 row-halves x 2 col-halves.
__global__ __launch_bounds__(256) void proj_kernel(const float* __restrict__ x,
                                                   const u16* __restrict__ wfrag,
                                                   u16* __restrict__ qb,
                                                   u16* __restrict__ kb,
                                                   u16* __restrict__ vT) {
  __shared__ float xs[2][32 * 64];    // [dbuf][tok][64 floats] chunk-swizzled, 8KB
  __shared__ u16  Ws[2][24 * 512];    // [dbuf][kk*12 + f][lane][8], 24KB

  int w = threadIdx.x >> 6, lane = threadIdx.x & 63;
  int ln = lane & 15, quad = lane >> 4;
  int rw = w >> 1, cs = w & 1;
  int s0 = blockIdx.x * 32;

  fx4 acc[6];
#pragma unroll
  for (int j = 0; j < 6; j++) acc[j] = (fx4){0.f, 0.f, 0.f, 0.f};

  // ---- staging (per round: 8KB x as 2 chunks/thread + 24KB W as 6 slabs/thread)
  // x rows are 64 floats = 16 chunks; XOR-swizzle within 8-chunk halves.
#define STAGE_X(rnd, buf)                                                      \
  {                                                                            \
    _Pragma("unroll")                                                          \
    for (int j = 0; j < 2; j++) {                                              \
      int cc = (w * 2 + j) * 64 + lane;                                        \
      int row = cc >> 4, c = cc & 15;                                          \
      int sc = (c & 8) | ((c ^ row) & 7);                                      \
      async16(x + (size_t)(s0 + row) * 768 + (rnd) * 64 + sc * 4,              \
              (char*)xs[buf] + (w * 2 + j) * 1024);                            \
    }                                                                          \
  }
#define STAGE_W(rnd, buf)                                                      \
  {                                                                            \
    _Pragma("unroll")                                                          \
    for (int m = 0; m < 3; m++)                                                \
      _Pragma("unroll")                                                        \
      for (int kk = 0; kk < 2; kk++)                                           \
        async16(wfrag + ((size_t)(m * KSTEPS + (rnd) * 2 + kk) * 256 +         \
                         w * 64 + lane) * 8,                                   \
                (char*)Ws[buf] + (kk * 12 + m * 4 + w) * 1024 + lane * 16);    \
  }

  STAGE_X(0, 0);
  STAGE_W(0, 0);

  int r = rw * 16 + ln;               // A-frag token row for this lane
  for (int rnd = 0; rnd < 12; rnd++) {
    __syncthreads();                  // publishes buf rnd&1
    if (rnd < 11) {
      STAGE_X(rnd + 1, (rnd + 1) & 1);
      STAGE_W(rnd + 1, (rnd + 1) & 1);
    }
    const float* xb = xs[rnd & 1];
    const u16*  wb = Ws[rnd & 1];
#pragma unroll
    for (int kk = 0; kk < 2; kk++) {
      int c0 = kk * 8 + 2 * quad;
      int sl0 = (c0 & 8) | ((c0 ^ r) & 7);
      int sl1 = ((c0 + 1) & 8) | (((c0 + 1) ^ r) & 7);
      fx4 xa = *(const fx4*)(xb + r * 64 + sl0 * 4);
      fx4 xv = *(const fx4*)(xb + r * 64 + sl1 * 4);
      short8 af;
#pragma unroll
      for (int j = 0; j < 4; j++) { af[j] = (short)f2bf(xa[j]); af[4 + j] = (short)f2bf(xv[j]); }
#pragma unroll
      for (int j = 0; j < 6; j++) {
        short8 bf = *(const short8*)(wb + (kk * 12 + cs * 6 + j) * 512 + lane * 8);
        acc[j] = mfma16(af, bf, acc[j]);
      }
    }
  }
#undef STAGE_X
#undef STAGE_W

  // epilogue: C/D layout col = lane&15, row = quad*4 + reg
  int tok0 = s0 + rw * 16 + quad * 4;
#pragma unroll
  for (int j = 0; j < 6; j++) {
    int f = cs * 6 + j;
    int d = (f & 3) * 16 + ln;
    if (f < 4) {
      // Q pre-scaled by 0.125 * log2(e): scores land in exp2 domain
#pragma unroll
      for (int reg = 0; reg < 4; reg++)
        qb[(size_t)(tok0 + reg) * 64 + d] = f2bf(acc[j][reg] * 0.180336887f);
    } else if (f < 8) {
#pragma unroll
      for (int reg = 0; reg < 4; reg++)
        kb[(size_t)(tok0 + reg) * 64 + d] = f2bf(acc[j][reg]);
    } else {
      int b = tok0 >> 12, s = tok0 & 4095;
      u16x4 vp;
#pragma unroll
      for (int reg = 0; reg < 4; reg++) vp[reg] = f2bf(acc[j][reg]);
      *(u16x4*)(vT + ((size_t)b * 64 + d) * 4096 + s) = vp;
    }
  }
}

// ---------------- flash attention v9 (unchanged): 32 Q-rows/wave, K+V DMA-staged
__global__ __launch_bounds__(256, 3) void attn_kernel(const u16* __restrict__ qb,
                                                      const u16* __restrict__ kb,
                                                      const u16* __restrict__ vT,
                                                      float* __restrict__ o0g,
                                                      float* __restrict__ po5,
                                                      float* __restrict__ mlb) {
  __shared__ u16 Kstg[2][4096];       // [buf][64 keys x 64 d]   16KB
  __shared__ u16 Vstg[2][4096];       // [buf][64 d x 64 keys]   16KB (V^T)
  __shared__ u16 Ps[4][32 * 72];      // per-wave P (32 rows), padded: 18KB

  int w = threadIdx.x >> 6, lane = threadIdx.x & 63;
  int ln = lane & 15, quad = lane >> 4;
  int band = 31 - blockIdx.x;         // 128-row band
  int b = blockIdx.y, z = blockIdx.z; // batch, split-K sixth
  int q0 = band * 128;
  int qw = q0 + w * 32;               // this wave's first Q-row (owns 32 rows)

  const u16* qbb = qb + (size_t)b * 4096 * 64;
  const u16* kbb = kb + (size_t)b * 4096 * 64;
  const u16* vtb = vT + (size_t)b * 64 * 4096;

  short8 qf0a = *(const short8*)(qbb + (size_t)(qw + ln) * 64 + quad * 8);
  short8 qf1a = *(const short8*)(qbb + (size_t)(qw + ln) * 64 + 32 + quad * 8);
  short8 qf0b = *(const short8*)(qbb + (size_t)(qw + 16 + ln) * 64 + quad * 8);
  short8 qf1b = *(const short8*)(qbb + (size_t)(qw + 16 + ln) * 64 + 32 + quad * 8);

  short8 ones;
#pragma unroll
  for (int j = 0; j < 8; j++) ones[j] = (short)0x3F80;   // bf16 1.0

  fx4 oa[4], ob[4];
#pragma unroll
  for (int j = 0; j < 4; j++) { oa[j] = (fx4){0.f,0.f,0.f,0.f}; ob[j] = (fx4){0.f,0.f,0.f,0.f}; }
  float la[4] = {0.f,0.f,0.f,0.f}, lb[4] = {0.f,0.f,0.f,0.f};

  int n = 2 * band + 2;               // 64-key tiles this band needs
  int c = (n + 5) / 6;                // tiles per split-K sixth
  int lo = z * c; if (lo > n) lo = n;
  int hi = lo + c; if (hi > n) hi = n;

  int t0c = w * 64 + lane;
  if (lo < hi) {
#pragma unroll
    for (int j = 0; j < 2; j++) {
      int cc = t0c + j * 256;
      int row = cc >> 3, slot = cc & 7, sw_ = (slot ^ (row & 7)) * 8;
      async16(kbb + ((size_t)lo * 64 + row) * 64 + sw_, (char*)Kstg[0] + cc * 16);
      async16(vtb + (size_t)row * 4096 + lo * 64 + sw_, (char*)Vstg[0] + cc * 16);
    }
  }

  for (int t = lo; t < hi; t++) {
    __syncthreads();                  // publishes buf (t-lo)&1
    if (t + 1 < hi) {
      int nb = (t - lo + 1) & 1;
#pragma unroll
      for (int j = 0; j < 2; j++) {
        int cc = t0c + j * 256;
        int row = cc >> 3, slot = cc & 7, sw_ = (slot ^ (row & 7)) * 8;
        async16(kbb + ((size_t)(t + 1) * 64 + row) * 64 + sw_, (char*)Kstg[nb] + cc * 16);
        async16(vtb + (size_t)row * 4096 + (t + 1) * 64 + sw_, (char*)Vstg[nb] + cc * 16);
      }
    }
    if (64 * t > qw + 31) continue;   // tile entirely above this wave's rows

    const u16* Kb = Kstg[(t - lo) & 1];
    const u16* Vb = Vstg[(t - lo) & 1];

    fx4 sAa[4], sAb[4];
#pragma unroll
    for (int nt = 0; nt < 4; nt++) {
      int row = nt * 16 + ln;
      int s0_ = quad ^ (row & 7), s1_ = (quad + 4) ^ (row & 7);
      short8 kf0 = *(const short8*)(Kb + (row * 8 + s0_) * 8);
      short8 kf1 = *(const short8*)(Kb + (row * 8 + s1_) * 8);
      sAa[nt] = mfma16(qf0a, kf0, (fx4){0.f,0.f,0.f,0.f});
      sAa[nt] = mfma16(qf1a, kf1, sAa[nt]);
      sAb[nt] = mfma16(qf0b, kf0, (fx4){0.f,0.f,0.f,0.f});
      sAb[nt] = mfma16(qf1b, kf1, sAb[nt]);
    }

    if (64 * t + 63 > qw) {
#pragma unroll
      for (int nt = 0; nt < 4; nt++)
#pragma unroll
        for (int reg = 0; reg < 4; reg++) {
          int col = t * 64 + nt * 16 + ln;
          int ra = qw + quad * 4 + reg;
          if (col > ra) sAa[nt][reg] = -1e30f;
          if (col > ra + 16) sAb[nt][reg] = -1e30f;
        }
    }

#pragma unroll
    for (int nt = 0; nt < 4; nt++)
#pragma unroll
      for (int reg = 0; reg < 4; reg++) {
        Ps[w][(quad * 4 + reg) * 72 + nt * 16 + ln] =
            p2bf(__builtin_amdgcn_exp2f(sAa[nt][reg]));
        Ps[w][(16 + quad * 4 + reg) * 72 + nt * 16 + ln] =
            p2bf(__builtin_amdgcn_exp2f(sAb[nt][reg]));
      }

    short8 pf0a = *(const short8*)(&Ps[w][ln * 72 + quad * 8]);
    short8 pf1a = *(const short8*)(&Ps[w][ln * 72 + 32 + quad * 8]);
    short8 pf0b = *(const short8*)(&Ps[w][(16 + ln) * 72 + quad * 8]);
    short8 pf1b = *(const short8*)(&Ps[w][(16 + ln) * 72 + 32 + quad * 8]);

    fx4 lacc = mfma16(pf0a, ones, (fx4){0.f,0.f,0.f,0.f});
    lacc = mfma16(pf1a, ones, lacc);
#pragma unroll
    for (int reg = 0; reg < 4; reg++) la[reg] += lacc[reg];
    lacc = mfma16(pf0b, ones, (fx4){0.f,0.f,0.f,0.f});
    lacc = mfma16(pf1b, ones, lacc);
#pragma unroll
    for (int reg = 0; reg < 4; reg++) lb[reg] += lacc[reg];

#pragma unroll
    for (int nt2 = 0; nt2 < 4; nt2++) {
      int row = nt2 * 16 + ln;
      int s0_ = quad ^ (row & 7), s1_ = (quad + 4) ^ (row & 7);
      short8 vf0 = *(const short8*)(Vb + (row * 8 + s0_) * 8);
      short8 vf1 = *(const short8*)(Vb + (row * 8 + s1_) * 8);
      oa[nt2] = mfma16(pf0a, vf0, oa[nt2]);
      oa[nt2] = mfma16(pf1a, vf1, oa[nt2]);
      ob[nt2] = mfma16(pf0b, vf0, ob[nt2]);
      ob[nt2] = mfma16(pf1b, vf1, ob[nt2]);
    }
  }

  float* dst = (z == 0) ? o0g : (po5 + (size_t)(z - 1) * 4 * 4096 * 64);
#pragma unroll
  for (int nt2 = 0; nt2 < 4; nt2++)
#pragma unroll
    for (int reg = 0; reg < 4; reg++) {
      int ra = qw + quad * 4 + reg;
      dst[((size_t)b * 4096 + ra) * 64 + nt2 * 16 + ln] = oa[nt2][reg];
      dst[((size_t)b * 4096 + ra + 16) * 64 + nt2 * 16 + ln] = ob[nt2][reg];
    }
  if (ln == 0) {
#pragma unroll
    for (int reg = 0; reg < 4; reg++) {
      int ra = qw + quad * 4 + reg;
      mlb[((size_t)z * 4 + b) * 4096 + ra] = la[reg];
      mlb[((size_t)z * 4 + b) * 4096 + ra + 16] = lb[reg];
    }
  }
}

// ---------------- merge the six split-K parts: out = Σo_z / Σl_z
__global__ __launch_bounds__(256) void merge_kernel(float* __restrict__ out,
                                                    const float* __restrict__ po5,
                                                    const float* __restrict__ mlb) {
  int qt = blockIdx.x, b = blockIdx.y;
  int r = threadIdx.x >> 3;
  int c = (threadIdx.x & 7) * 8;
  size_t row = (size_t)b * 4096 + qt * 32 + r;
  float l = mlb[row];
#pragma unroll
  for (int z = 1; z < 6; z++) l += mlb[(size_t)z * 4 * 4096 + row];
  float inv = 1.0f / l;
  float* op = out + row * 64 + c;
  fx4 u0 = *(fx4*)op, u1 = *(fx4*)(op + 4);
#pragma unroll
  for (int z = 1; z < 6; z++) {
    const float* pp = po5 + (size_t)(z - 1) * 4 * 4096 * 64 + row * 64 + c;
    fx4 v0 = *(const fx4*)pp, v1 = *(const fx4*)(pp + 4);
#pragma unroll
    for (int j = 0; j < 4; j++) { u0[j] += v0[j]; u1[j] += v1[j]; }
  }
#pragma unroll
  for (int j = 0; j < 4; j++) { u0[j] *= inv; u1[j] *= inv; }
  *(fx4*)op = u0;
  *(fx4*)(op + 4) = u1;
}

extern "C" void kernel_launch(void* const* d_in, const int* in_sizes, int n_in,
                              void* d_out, int out_size, void* d_ws, size_t ws_size,
                              hipStream_t stream) {
  const float* x  = (const float*)d_in[0];
  const float* Wq = (const float*)d_in[1];
  const float* Wk = (const float*)d_in[2];
  const float* Wv = (const float*)d_in[3];

  u16* qbw = (u16*)d_ws;                          // [16384][64] bf16, 2MB
  u16* kbw = qbw + (size_t)TOKENS * 64;           // 2MB
  u16* vtw = kbw + (size_t)TOKENS * 64;           // 2MB
  u16* wfr = vtw + (size_t)TOKENS * 64;           // 288KB
  float* po5 = (float*)(wfr + (size_t)3 * KSTEPS * 256 * 8);  // 5x [4][4096][64] fp32, 20MB
  float* mlb = po5 + (size_t)5 * 4 * 4096 * 64;   // [6][4][4096] float, 384KB

  prep_w_kernel<<<72, 256, 0, stream>>>(Wq, Wk, Wv, wfr);
  proj_kernel<<<TOKENS / 32, 256, 0, stream>>>(x, wfr, qbw, kbw, vtw);
  attn_kernel<<<dim3(32, 4, 6), 256, 0, stream>>>(qbw, kbw, vtw,
                                                  (float*)d_out, po5, mlb);
  merge_kernel<<<dim3(128, 4), 256, 0, stream>>>((float*)d_out, po5, mlb);
}